// Round 11
// baseline (80.454 us; speedup 1.0000x reference)
//
#include <hip/hip_runtime.h>
#include <math.h>

// Chamfer distance: B=4, N=M=4096, D=3, fp32 — MFMA, atomic-free.
//
// R10 lesson: 13-slot split-bf16 MFMA d2 is VALIDATED (absmax 0.0156,
// 4.7x margin) but 1.3M device atomicMin (64-way contention, 16 addr/line,
// cross-XCD ping-pong) ate the gain (main ~20us). R11: compute each
// direction separately (MFMA makes 2x d2 nearly free: ~1us total). Block =
// 64 query rows x ALL 4096 refs (4 chunks x 32KB LDS) -> row-mins are
// block-complete -> plain coalesced stores. ZERO atomics.
// d2 = q2 + r2 - 2 q.r as 13 K-slots of mfma_f32_16x16x32_bf16:
//   k0-2:(-2qh)*rh  k3-5:(-2ql)*rh  k6-8:(-2qh)*rl
//   k9-10:(q2h,q2l)*1  k11-12:1*(r2h,r2l)  k13-31: zero (A quads 2-3 = 0)
// Layouts (guide-verified): A[m=lane&15][k=quad*8+j], B[n=lane&15][k=...],
// D: col=lane&15, row=quad*4+reg.

typedef __attribute__((ext_vector_type(8))) short bf16x8;
typedef __attribute__((ext_vector_type(4))) float f32x4;

#define NPTS    4096
#define NBATCH  4
#define QG      64                    // query rows per block
#define CHUNK   1024                  // refs staged per LDS pass
#define NCHUNK  (NPTS / CHUNK)        // 4
#define ONE_BF  ((short)0x3F80)
#define SCALE   (50.0f / (float)(NBATCH * NPTS))

__device__ __forceinline__ unsigned short bf_rne(float v) {
    unsigned int u = __float_as_uint(v);
    u += 0x7FFFu + ((u >> 16) & 1u);
    return (unsigned short)(u >> 16);
}
__device__ __forceinline__ float bf_f(unsigned short s) {
    return __uint_as_float(((unsigned int)s) << 16);
}
__device__ __forceinline__ void split2(float v, short& h, short& l) {
    unsigned short hh = bf_rne(v);
    h = (short)hh;
    l = (short)bf_rne(v - bf_f(hh));
}

__global__ __launch_bounds__(256, 4) void chamfer_mfma(
    const float* __restrict__ a1, const float* __restrict__ a2,
    float* __restrict__ rmins)
{
    __shared__ bf16x8 Bp0[CHUNK];   // B k0-7 per ref point (16 KB)
    __shared__ bf16x8 Bp1[CHUNK];   // B k8-15 (16 KB)
    __shared__ bf16x8 Ap0[QG];      // A k0-7 per query row
    __shared__ bf16x8 Ap1[QG];      // A k8-15
    __shared__ float  pm2[4][QG];   // per-wave partial row-mins

    const int bid = blockIdx.x;
    const int rg  = bid & 63;              // query row-group
    const int b   = (bid >> 6) & 3;
    const int dir = bid >> 8;              // 0: q=a1,r=a2 ; 1: q=a2,r=a1
    const float* q = (dir == 0) ? a1 : a2;
    const float* r = (dir == 0) ? a2 : a1;
    const float* qbase = q + ((size_t)b * NPTS + (size_t)rg * QG) * 3;
    const float* rbase = r + (size_t)b * NPTS * 3;

    const int tid  = threadIdx.x;
    const int w    = tid >> 6;
    const int lane = tid & 63;
    const int quad = lane >> 4;
    const int c    = lane & 15;

    // ---- Pack A side (this block's 64 queries) once ----
    if (tid < QG) {
        float x = qbase[3 * tid + 0];
        float y = qbase[3 * tid + 1];
        float z = qbase[3 * tid + 2];
        float q2 = fmaf(x, x, fmaf(y, y, z * z));
        short axh, axl, ayh, ayl, azh, azl, qh, ql;
        split2(-2.0f * x, axh, axl);
        split2(-2.0f * y, ayh, ayl);
        split2(-2.0f * z, azh, azl);
        split2(q2, qh, ql);
        bf16x8 p0 = {axh, ayh, azh, axl, ayl, azl, axh, ayh};
        bf16x8 p1 = {azh, qh, ql, ONE_BF, 0, 0, 0, 0};
        Ap0[tid] = p0; Ap1[tid] = p1;
    }

    const bf16x8 zf = {0, 0, 0, 0, 0, 0, 0, 0};
    const f32x4  zc = {0.f, 0.f, 0.f, 0.f};

    bf16x8 af0 = zf, af1 = zf, af2 = zf, af3 = zf;   // row-tiles 0..3
    float rowacc[16];
    #pragma unroll
    for (int i = 0; i < 16; ++i) rowacc[i] = INFINITY;

    for (int ch = 0; ch < NCHUNK; ++ch) {
        if (ch) __syncthreads();   // protect Bp reuse
        // ---- Stage + pack 1024 refs: 4 points per thread ----
        #pragma unroll
        for (int i = 0; i < CHUNK / 256; ++i) {
            const int m = tid + i * 256;
            const int g = ch * CHUNK + m;
            float x = rbase[3 * g + 0];
            float y = rbase[3 * g + 1];
            float z = rbase[3 * g + 2];
            float r2 = fmaf(x, x, fmaf(y, y, z * z));
            short xh, xl, yh, yl, zh, zl, rh, rl;
            split2(x, xh, xl); split2(y, yh, yl); split2(z, zh, zl);
            split2(r2, rh, rl);
            bf16x8 p0 = {xh, yh, zh, xh, yh, zh, xl, yl};
            bf16x8 p1 = {zl, ONE_BF, ONE_BF, rh, rl, 0, 0, 0};
            Bp0[m] = p0; Bp1[m] = p1;
        }
        __syncthreads();

        if (ch == 0) {   // A frags: quads 2-3 keep zero (K upper half)
            if (quad == 0) {
                af0 = Ap0[c]; af1 = Ap0[16 + c];
                af2 = Ap0[32 + c]; af3 = Ap0[48 + c];
            } else if (quad == 1) {
                af0 = Ap1[c]; af1 = Ap1[16 + c];
                af2 = Ap1[32 + c]; af3 = Ap1[48 + c];
            }
        }

        // ---- 64 col-tiles per chunk; wave w takes tiles 4k+w ----
        #pragma unroll 4
        for (int ct = 0; ct < 16; ++ct) {
            const int mb = (ct * 4 + w) * 16;
            bf16x8 bfr = zf;
            if (quad == 0)      bfr = Bp0[mb + c];
            else if (quad == 1) bfr = Bp1[mb + c];

            f32x4 d;
            d = __builtin_amdgcn_mfma_f32_16x16x32_bf16(af0, bfr, zc, 0, 0, 0);
            rowacc[0] = fminf(rowacc[0], d[0]);  rowacc[1] = fminf(rowacc[1], d[1]);
            rowacc[2] = fminf(rowacc[2], d[2]);  rowacc[3] = fminf(rowacc[3], d[3]);
            d = __builtin_amdgcn_mfma_f32_16x16x32_bf16(af1, bfr, zc, 0, 0, 0);
            rowacc[4] = fminf(rowacc[4], d[0]);  rowacc[5] = fminf(rowacc[5], d[1]);
            rowacc[6] = fminf(rowacc[6], d[2]);  rowacc[7] = fminf(rowacc[7], d[3]);
            d = __builtin_amdgcn_mfma_f32_16x16x32_bf16(af2, bfr, zc, 0, 0, 0);
            rowacc[8] = fminf(rowacc[8], d[0]);  rowacc[9] = fminf(rowacc[9], d[1]);
            rowacc[10] = fminf(rowacc[10], d[2]); rowacc[11] = fminf(rowacc[11], d[3]);
            d = __builtin_amdgcn_mfma_f32_16x16x32_bf16(af3, bfr, zc, 0, 0, 0);
            rowacc[12] = fminf(rowacc[12], d[0]); rowacc[13] = fminf(rowacc[13], d[1]);
            rowacc[14] = fminf(rowacc[14], d[2]); rowacc[15] = fminf(rowacc[15], d[3]);
        }
    }

    // ---- Row-min reduce over the 16 col-lanes (bits 0-3) ----
    #pragma unroll
    for (int st = 1; st <= 8; st <<= 1) {
        #pragma unroll
        for (int i = 0; i < 16; ++i)
            rowacc[i] = fminf(rowacc[i], __shfl_xor(rowacc[i], st));
    }
    // Lane c==0 of each quad holds rows t*16 + quad*4 + r (t=i>>2, r=i&3).
    if (c == 0) {
        #pragma unroll
        for (int i = 0; i < 16; ++i)
            pm2[w][(i >> 2) * 16 + quad * 4 + (i & 3)] = rowacc[i];
    }
    __syncthreads();

    // Combine the 4 waves' partials, clamp, plain coalesced store.
    if (tid < QG) {
        float m = fminf(fminf(pm2[0][tid], pm2[1][tid]),
                        fminf(pm2[2][tid], pm2[3][tid]));
        rmins[(size_t)bid * QG + tid] = fmaxf(m, 0.0f);
    }
}

// Sum all 32768 row-mins, scale, write the scalar.
__global__ __launch_bounds__(1024) void chamfer_final(
    const float* __restrict__ rmins, float* __restrict__ out)
{
    float s = 0.0f;
    for (int i = threadIdx.x; i < 2 * NBATCH * NPTS; i += 1024)
        s += rmins[i];
    for (int off = 32; off > 0; off >>= 1) s += __shfl_down(s, off);
    __shared__ float wsum[16];
    if ((threadIdx.x & 63) == 0) wsum[threadIdx.x >> 6] = s;
    __syncthreads();
    if (threadIdx.x < 64) {
        float v = (threadIdx.x < 16) ? wsum[threadIdx.x] : 0.0f;
        for (int off = 8; off > 0; off >>= 1) v += __shfl_down(v, off);
        if (threadIdx.x == 0) out[0] = v * SCALE;
    }
}

extern "C" void kernel_launch(void* const* d_in, const int* in_sizes, int n_in,
                              void* d_out, int out_size, void* d_ws, size_t ws_size,
                              hipStream_t stream) {
    const float* a1 = (const float*)d_in[0];
    const float* a2 = (const float*)d_in[1];
    float* out   = (float*)d_out;
    float* rmins = (float*)d_ws;   // 32768 floats, fully written by main

    chamfer_mfma<<<2 * NBATCH * (NPTS / QG), 256, 0, stream>>>(a1, a2, rmins);
    chamfer_final<<<1, 1024, 0, stream>>>(rmins, out);
}